// Round 3
// baseline (1082.278 us; speedup 1.0000x reference)
//
#include <hip/hip_runtime.h>

#define LEAKY 0.2f
#define BSH 7
#define BN 128   // nodes per bucket = 1<<BSH

__device__ __forceinline__ float wave_reduce_add64(float v) {
  #pragma unroll
  for (int m = 1; m < 64; m <<= 1) v += __shfl_xor(v, m, 64);
  return v;
}

// ---------------- Tiled GEMM + fused attention dots ----------------
template<int K, int CO, int H>
__global__ __launch_bounds__(256)
void gat_gemm2(const float* __restrict__ x, const float* __restrict__ W,
               const float* __restrict__ atts, const float* __restrict__ attd,
               float* __restrict__ h, float* __restrict__ sa, float* __restrict__ da,
               int N) {
  constexpr int CG = CO / 4;
  constexpr int BM = (256 / CG) * 4;
  constexpr int BK = 64;
  constexpr int NK = K / BK;
  constexpr int C = CO / H;

  __shared__ float xs[BM][BK + 4];
  __shared__ float ws[CO][K + 4];

  const int t = (int)threadIdx.x;
  const int cg = t % CG;
  const int ng = t / CG;
  const int n0 = (int)blockIdx.x * BM;

  constexpr int WF4 = CO * K / 4;
  for (int f = t; f < WF4; f += 256) {
    const int r = f / (K / 4), c4 = f % (K / 4);
    *(float4*)&ws[r][c4 * 4] = *(const float4*)(W + (size_t)r * K + c4 * 4);
  }

  float acc[4][4] = {};

  for (int kb = 0; kb < NK; ++kb) {
    __syncthreads();
    constexpr int XF4 = BM * BK / 4;
    for (int f = t; f < XF4; f += 256) {
      const int r = f / (BK / 4), c4 = f % (BK / 4);
      int row = n0 + r; row = row < N ? row : N - 1;
      *(float4*)&xs[r][c4 * 4] = *(const float4*)(x + (size_t)row * K + kb * BK + c4 * 4);
    }
    __syncthreads();
    #pragma unroll
    for (int k = 0; k < BK; k += 4) {
      float4 xa[4], wb[4];
      #pragma unroll
      for (int i = 0; i < 4; ++i) xa[i] = *(const float4*)&xs[ng * 4 + i][k];
      #pragma unroll
      for (int j = 0; j < 4; ++j) wb[j] = *(const float4*)&ws[cg + CG * j][kb * BK + k];
      #pragma unroll
      for (int i = 0; i < 4; ++i) {
        #pragma unroll
        for (int j = 0; j < 4; ++j) {
          acc[i][j] = fmaf(xa[i].x, wb[j].x, acc[i][j]);
          acc[i][j] = fmaf(xa[i].y, wb[j].y, acc[i][j]);
          acc[i][j] = fmaf(xa[i].z, wb[j].z, acc[i][j]);
          acc[i][j] = fmaf(xa[i].w, wb[j].w, acc[i][j]);
        }
      }
    }
  }

  float as_[4], ad_[4];
  #pragma unroll
  for (int j = 0; j < 4; ++j) {
    as_[j] = atts[cg + CG * j];
    ad_[j] = attd[cg + CG * j];
  }
  float ps[4][H] = {}, pd[4][H] = {};
  #pragma unroll
  for (int i = 0; i < 4; ++i) {
    #pragma unroll
    for (int j = 0; j < 4; ++j) {
      const int hd = (CG * j) / C;
      ps[i][hd] = fmaf(acc[i][j], as_[j], ps[i][hd]);
      pd[i][hd] = fmaf(acc[i][j], ad_[j], pd[i][hd]);
    }
  }
  #pragma unroll
  for (int m = 1; m < CG; m <<= 1) {
    #pragma unroll
    for (int i = 0; i < 4; ++i) {
      #pragma unroll
      for (int hd = 0; hd < H; ++hd) {
        ps[i][hd] += __shfl_xor(ps[i][hd], m, 64);
        pd[i][hd] += __shfl_xor(pd[i][hd], m, 64);
      }
    }
  }

  #pragma unroll
  for (int i = 0; i < 4; ++i) {
    const int n = n0 + ng * 4 + i;
    if (n < N) {
      #pragma unroll
      for (int j = 0; j < 4; ++j) h[(size_t)n * CO + cg + CG * j] = acc[i][j];
      if (cg == 0) {
        #pragma unroll
        for (int hd = 0; hd < H; ++hd) {
          sa[n * H + hd] = ps[i][hd];
          da[n * H + hd] = pd[i][hd];
        }
      }
    }
  }
}

// ---------------- Edge aggregation (CSR by dst), 4x unrolled ----------------
template<int H, int C, bool LN>
__global__ __launch_bounds__(256)
void gat_edge(const float* __restrict__ h, const float* __restrict__ sa,
              const float* __restrict__ da, const int* __restrict__ rowp,
              const int* __restrict__ col, const float* __restrict__ bias,
              const float* __restrict__ gamma, const float* __restrict__ beta,
              float* __restrict__ out, int N) {
  constexpr int HC = H * C;
  constexpr int NPW = 64 / HC;
  static_assert(!LN || NPW == 1, "LN needs full wave per node");
  const int lane = (int)(threadIdx.x & 63);
  const int wave = (int)((blockIdx.x * blockDim.x + threadIdx.x) >> 6);
  const int sub = lane / HC;
  const int cc = lane % HC;
  const int head = cc / C;
  const int n = wave * NPW + sub;
  const bool valid = (n < N);
  const int nc = valid ? n : 0;
  const int beg = rowp[nc];
  const int end = rowp[nc + 1];
  const float dv = da[nc * H + head];

  float acc0 = 0.f, acc1 = 0.f, acc2 = 0.f, acc3 = 0.f;
  float ws0 = 0.f, ws1 = 0.f, ws2 = 0.f, ws3 = 0.f;
  int i = beg;
  for (; i + 4 <= end; i += 4) {
    const int s0 = col[i], s1 = col[i + 1], s2 = col[i + 2], s3 = col[i + 3];
    float l0 = sa[s0 * H + head] + dv;
    float l1 = sa[s1 * H + head] + dv;
    float l2 = sa[s2 * H + head] + dv;
    float l3 = sa[s3 * H + head] + dv;
    const float h0 = h[(size_t)s0 * HC + cc];
    const float h1 = h[(size_t)s1 * HC + cc];
    const float h2 = h[(size_t)s2 * HC + cc];
    const float h3 = h[(size_t)s3 * HC + cc];
    l0 = l0 >= 0.f ? l0 : LEAKY * l0;
    l1 = l1 >= 0.f ? l1 : LEAKY * l1;
    l2 = l2 >= 0.f ? l2 : LEAKY * l2;
    l3 = l3 >= 0.f ? l3 : LEAKY * l3;
    const float w0 = __expf(l0), w1 = __expf(l1), w2 = __expf(l2), w3 = __expf(l3);
    ws0 += w0; ws1 += w1; ws2 += w2; ws3 += w3;
    acc0 = fmaf(w0, h0, acc0);
    acc1 = fmaf(w1, h1, acc1);
    acc2 = fmaf(w2, h2, acc2);
    acc3 = fmaf(w3, h3, acc3);
  }
  for (; i < end; ++i) {
    const int s = col[i];
    float lg = sa[s * H + head] + dv;
    lg = lg >= 0.f ? lg : LEAKY * lg;
    const float w = __expf(lg);
    ws0 += w;
    acc0 = fmaf(w, h[(size_t)s * HC + cc], acc0);
  }
  const float wsum = (ws0 + ws1) + (ws2 + ws3);
  const float acc = (acc0 + acc1) + (acc2 + acc3);

  float v = acc / fmaxf(wsum, 1e-16f) + h[(size_t)nc * HC + cc] + bias[cc];
  if constexpr (LN) {
    const float mu = wave_reduce_add64(v) * (1.f / 64.f);
    const float d = v - mu;
    const float var = wave_reduce_add64(d * d) * (1.f / 64.f);
    float y = d * rsqrtf(var + 1e-5f) * gamma[cc] + beta[cc];
    v = fmaxf(y, 0.f);
  }
  if (valid) out[(size_t)n * HC + cc] = v;
}

// ---------------- CSR build via 2-level bucketing ----------------
// Bucket = 128 consecutive dst nodes. All scattered writes land in small
// cache-resident windows -> ~compulsory traffic instead of 64B/edge.

__global__ void k_bcount(const int* __restrict__ dst, int* __restrict__ bcnt, int E) {
  int e = blockIdx.x * blockDim.x + threadIdx.x;
  if (e < E) atomicAdd(&bcnt[dst[e] >> BSH], 1);
}

// one block, 256 threads, scans up to 1024 bucket counts
__global__ void k_bscan(const int* __restrict__ bcnt, int nb,
                        int* __restrict__ bstart, int* __restrict__ bcur,
                        int* __restrict__ rowp_last, int E) {
  __shared__ int sm[256];
  const int t = (int)threadIdx.x;
  int v[4];
  #pragma unroll
  for (int j = 0; j < 4; ++j) { int i = t * 4 + j; v[j] = (i < nb) ? bcnt[i] : 0; }
  const int tot = v[0] + v[1] + v[2] + v[3];
  sm[t] = tot; __syncthreads();
  #pragma unroll
  for (int off = 1; off < 256; off <<= 1) {
    int xv = (t >= off) ? sm[t - off] : 0;
    __syncthreads();
    sm[t] += xv;
    __syncthreads();
  }
  int excl = sm[t] - tot;
  #pragma unroll
  for (int j = 0; j < 4; ++j) {
    int i = t * 4 + j;
    if (i < nb) { bstart[i] = excl; bcur[i] = excl; excl += v[j]; }
  }
  if (t == 0) { bstart[nb] = E; *rowp_last = E; }
}

// pack (src, local_dst) into one int: src<<BSH | (dst & (BN-1))
__global__ void k_bscatter(const int* __restrict__ src, const int* __restrict__ dst,
                           int* __restrict__ bcur, int* __restrict__ pairs, int E) {
  int e = blockIdx.x * blockDim.x + threadIdx.x;
  if (e < E) {
    const int d = dst[e];
    const int p = atomicAdd(&bcur[d >> BSH], 1);
    pairs[p] = (src[e] << BSH) | (d & (BN - 1));
  }
}

// one workgroup per bucket: LDS histogram + scan + LDS-cursor scatter.
__global__ __launch_bounds__(256)
void k_bucket_csr(const int* __restrict__ pairs, const int* __restrict__ bstart,
                  int* __restrict__ rowp, int* __restrict__ col, int N) {
  __shared__ int ldeg[BN];
  __shared__ int lofs[BN];
  const int b = (int)blockIdx.x;
  const int t = (int)threadIdx.x;
  const int base = b << BSH;
  const int nn = min(BN, N - base);
  const int s0 = bstart[b];
  const int s1 = bstart[b + 1];

  if (t < BN) ldeg[t] = 0;
  __syncthreads();
  for (int i = s0 + t; i < s1; i += 256)
    atomicAdd(&ldeg[pairs[i] & (BN - 1)], 1);
  __syncthreads();
  if (t < BN) lofs[t] = ldeg[t];
  __syncthreads();
  #pragma unroll
  for (int off = 1; off < BN; off <<= 1) {
    int v = (t < BN && t >= off) ? lofs[t - off] : 0;
    __syncthreads();
    if (t < BN) lofs[t] += v;
    __syncthreads();
  }
  if (t < BN) {
    const int ofs = s0 + lofs[t] - ldeg[t];   // exclusive start for node base+t
    if (t < nn) rowp[base + t] = ofs;
    ldeg[t] = ofs;                            // becomes the scatter cursor
  }
  __syncthreads();
  for (int i = s0 + t; i < s1; i += 256) {
    const int pr = pairs[i];
    const int p = atomicAdd(&ldeg[pr & (BN - 1)], 1);
    col[p] = pr >> BSH;
  }
}

extern "C" void kernel_launch(void* const* d_in, const int* in_sizes, int n_in,
                              void* d_out, int out_size, void* d_ws, size_t ws_size,
                              hipStream_t stream) {
  const float* x   = (const float*)d_in[0];
  const int* esrc  = (const int*)d_in[1];
  const int* edst  = (const int*)d_in[2];
  const float* W1  = (const float*)d_in[3];
  const float* as1 = (const float*)d_in[4];
  const float* ad1 = (const float*)d_in[5];
  const float* b1  = (const float*)d_in[6];
  const float* W2  = (const float*)d_in[7];
  const float* as2 = (const float*)d_in[8];
  const float* ad2 = (const float*)d_in[9];
  const float* b2  = (const float*)d_in[10];
  const float* W3  = (const float*)d_in[11];
  const float* as3 = (const float*)d_in[12];
  const float* ad3 = (const float*)d_in[13];
  const float* b3  = (const float*)d_in[14];
  const float* g1  = (const float*)d_in[15];
  const float* be1 = (const float*)d_in[16];
  const float* g2  = (const float*)d_in[17];
  const float* be2 = (const float*)d_in[18];

  const int N = in_sizes[0] / 128;
  const int E = in_sizes[1];
  const int NB = (N + BN - 1) / BN;

  char* ws = (char*)d_ws;
  size_t off = 0;
  auto alloc = [&](size_t bytes) -> void* {
    void* p = ws + off;
    off = (off + bytes + 255) & ~(size_t)255;
    return p;
  };
  float* hbuf  = (float*)alloc((size_t)N * 64 * 4);
  float* lnbuf = (float*)alloc((size_t)N * 64 * 4);
  float* sab   = (float*)alloc((size_t)N * 2 * 4);
  float* dab   = (float*)alloc((size_t)N * 2 * 4);
  int* rowp    = (int*)alloc((size_t)(N + 1) * 4);
  int* colb    = (int*)alloc((size_t)E * 4);
  int* bcnt    = (int*)alloc((size_t)NB * 4);
  int* bstart  = (int*)alloc((size_t)(NB + 1) * 4);
  int* bcur    = (int*)alloc((size_t)NB * 4);
  // pairs buffer: reuse d_out (out is N*32 floats = 12.8MB >= E*4 = 6.4MB);
  // its lifetime ends before the final layer writes d_out.
  int* pairs = (E <= out_size) ? (int*)d_out : (int*)alloc((size_t)E * 4);
  (void)ws_size; (void)n_in;

  // ---- CSR build (2-level bucket) ----
  hipMemsetAsync(bcnt, 0, (size_t)NB * 4, stream);
  const int gE = (E + 255) / 256;
  k_bcount<<<gE, 256, 0, stream>>>(edst, bcnt, E);
  k_bscan<<<1, 256, 0, stream>>>(bcnt, NB, bstart, bcur, rowp + N, E);
  k_bscatter<<<gE, 256, 0, stream>>>(esrc, edst, bcur, pairs, E);
  k_bucket_csr<<<NB, 256, 0, stream>>>(pairs, bstart, rowp, colb, N);

  const int gG12 = (N + 63) / 64;
  const int gG3  = (N + 127) / 128;
  const int gEdge  = (N + 3) / 4;
  const int gEdge3 = (N + 7) / 8;

  // ---- Layer 1: 128 -> (2x32) + LN + ReLU ----
  gat_gemm2<128, 64, 2><<<gG12, 256, 0, stream>>>(x, W1, as1, ad1, hbuf, sab, dab, N);
  gat_edge<2, 32, true><<<gEdge, 256, 0, stream>>>(hbuf, sab, dab, rowp, colb, b1, g1, be1, lnbuf, N);

  // ---- Layer 2: 64 -> (2x32) + LN + ReLU ----
  gat_gemm2<64, 64, 2><<<gG12, 256, 0, stream>>>(lnbuf, W2, as2, ad2, hbuf, sab, dab, N);
  gat_edge<2, 32, true><<<gEdge, 256, 0, stream>>>(hbuf, sab, dab, rowp, colb, b2, g2, be2, lnbuf, N);

  // ---- Layer 3: 64 -> (1x32), no LN ----
  gat_gemm2<64, 32, 1><<<gG3, 256, 0, stream>>>(lnbuf, W3, as3, ad3, hbuf, sab, dab, N);
  gat_edge<1, 32, false><<<gEdge3, 256, 0, stream>>>(hbuf, sab, dab, rowp, colb, b3, nullptr, nullptr,
                                                     (float*)d_out, N);
}

// Round 4
// 365.780 us; speedup vs baseline: 2.9588x; 2.9588x over previous
//
#include <hip/hip_runtime.h>

#define LEAKY 0.2f
#define BSH 7
#define BN 128      // nodes per bucket = 1<<BSH
#define CHUNK 8192  // edges per partition workgroup
#define NBMAX 1024  // max buckets supported by LDS arrays

__device__ __forceinline__ float wave_reduce_add64(float v) {
  #pragma unroll
  for (int m = 1; m < 64; m <<= 1) v += __shfl_xor(v, m, 64);
  return v;
}

// ---------------- Tiled GEMM + fused attention dots ----------------
template<int K, int CO, int H>
__global__ __launch_bounds__(256)
void gat_gemm2(const float* __restrict__ x, const float* __restrict__ W,
               const float* __restrict__ atts, const float* __restrict__ attd,
               float* __restrict__ h, float* __restrict__ sa, float* __restrict__ da,
               int N) {
  constexpr int CG = CO / 4;
  constexpr int BM = (256 / CG) * 4;
  constexpr int BK = 64;
  constexpr int NK = K / BK;
  constexpr int C = CO / H;

  __shared__ float xs[BM][BK + 4];
  __shared__ float ws[CO][K + 4];

  const int t = (int)threadIdx.x;
  const int cg = t % CG;
  const int ng = t / CG;
  const int n0 = (int)blockIdx.x * BM;

  constexpr int WF4 = CO * K / 4;
  for (int f = t; f < WF4; f += 256) {
    const int r = f / (K / 4), c4 = f % (K / 4);
    *(float4*)&ws[r][c4 * 4] = *(const float4*)(W + (size_t)r * K + c4 * 4);
  }

  float acc[4][4] = {};

  for (int kb = 0; kb < NK; ++kb) {
    __syncthreads();
    constexpr int XF4 = BM * BK / 4;
    for (int f = t; f < XF4; f += 256) {
      const int r = f / (BK / 4), c4 = f % (BK / 4);
      int row = n0 + r; row = row < N ? row : N - 1;
      *(float4*)&xs[r][c4 * 4] = *(const float4*)(x + (size_t)row * K + kb * BK + c4 * 4);
    }
    __syncthreads();
    #pragma unroll
    for (int k = 0; k < BK; k += 4) {
      float4 xa[4], wb[4];
      #pragma unroll
      for (int i = 0; i < 4; ++i) xa[i] = *(const float4*)&xs[ng * 4 + i][k];
      #pragma unroll
      for (int j = 0; j < 4; ++j) wb[j] = *(const float4*)&ws[cg + CG * j][kb * BK + k];
      #pragma unroll
      for (int i = 0; i < 4; ++i) {
        #pragma unroll
        for (int j = 0; j < 4; ++j) {
          acc[i][j] = fmaf(xa[i].x, wb[j].x, acc[i][j]);
          acc[i][j] = fmaf(xa[i].y, wb[j].y, acc[i][j]);
          acc[i][j] = fmaf(xa[i].z, wb[j].z, acc[i][j]);
          acc[i][j] = fmaf(xa[i].w, wb[j].w, acc[i][j]);
        }
      }
    }
  }

  float as_[4], ad_[4];
  #pragma unroll
  for (int j = 0; j < 4; ++j) {
    as_[j] = atts[cg + CG * j];
    ad_[j] = attd[cg + CG * j];
  }
  float ps[4][H] = {}, pd[4][H] = {};
  #pragma unroll
  for (int i = 0; i < 4; ++i) {
    #pragma unroll
    for (int j = 0; j < 4; ++j) {
      const int hd = (CG * j) / C;
      ps[i][hd] = fmaf(acc[i][j], as_[j], ps[i][hd]);
      pd[i][hd] = fmaf(acc[i][j], ad_[j], pd[i][hd]);
    }
  }
  #pragma unroll
  for (int m = 1; m < CG; m <<= 1) {
    #pragma unroll
    for (int i = 0; i < 4; ++i) {
      #pragma unroll
      for (int hd = 0; hd < H; ++hd) {
        ps[i][hd] += __shfl_xor(ps[i][hd], m, 64);
        pd[i][hd] += __shfl_xor(pd[i][hd], m, 64);
      }
    }
  }

  #pragma unroll
  for (int i = 0; i < 4; ++i) {
    const int n = n0 + ng * 4 + i;
    if (n < N) {
      #pragma unroll
      for (int j = 0; j < 4; ++j) h[(size_t)n * CO + cg + CG * j] = acc[i][j];
      if (cg == 0) {
        #pragma unroll
        for (int hd = 0; hd < H; ++hd) {
          sa[n * H + hd] = ps[i][hd];
          da[n * H + hd] = pd[i][hd];
        }
      }
    }
  }
}

// ---------------- Edge aggregation (CSR by dst), 4x unrolled ----------------
template<int H, int C, bool LN>
__global__ __launch_bounds__(256)
void gat_edge(const float* __restrict__ h, const float* __restrict__ sa,
              const float* __restrict__ da, const int* __restrict__ rowp,
              const int* __restrict__ col, const float* __restrict__ bias,
              const float* __restrict__ gamma, const float* __restrict__ beta,
              float* __restrict__ out, int N) {
  constexpr int HC = H * C;
  constexpr int NPW = 64 / HC;
  static_assert(!LN || NPW == 1, "LN needs full wave per node");
  const int lane = (int)(threadIdx.x & 63);
  const int wave = (int)((blockIdx.x * blockDim.x + threadIdx.x) >> 6);
  const int sub = lane / HC;
  const int cc = lane % HC;
  const int head = cc / C;
  const int n = wave * NPW + sub;
  const bool valid = (n < N);
  const int nc = valid ? n : 0;
  const int beg = rowp[nc];
  const int end = rowp[nc + 1];
  const float dv = da[nc * H + head];

  float acc0 = 0.f, acc1 = 0.f, acc2 = 0.f, acc3 = 0.f;
  float ws0 = 0.f, ws1 = 0.f, ws2 = 0.f, ws3 = 0.f;
  int i = beg;
  for (; i + 4 <= end; i += 4) {
    const int s0 = col[i], s1 = col[i + 1], s2 = col[i + 2], s3 = col[i + 3];
    float l0 = sa[s0 * H + head] + dv;
    float l1 = sa[s1 * H + head] + dv;
    float l2 = sa[s2 * H + head] + dv;
    float l3 = sa[s3 * H + head] + dv;
    const float h0 = h[(size_t)s0 * HC + cc];
    const float h1 = h[(size_t)s1 * HC + cc];
    const float h2 = h[(size_t)s2 * HC + cc];
    const float h3 = h[(size_t)s3 * HC + cc];
    l0 = l0 >= 0.f ? l0 : LEAKY * l0;
    l1 = l1 >= 0.f ? l1 : LEAKY * l1;
    l2 = l2 >= 0.f ? l2 : LEAKY * l2;
    l3 = l3 >= 0.f ? l3 : LEAKY * l3;
    const float w0 = __expf(l0), w1 = __expf(l1), w2 = __expf(l2), w3 = __expf(l3);
    ws0 += w0; ws1 += w1; ws2 += w2; ws3 += w3;
    acc0 = fmaf(w0, h0, acc0);
    acc1 = fmaf(w1, h1, acc1);
    acc2 = fmaf(w2, h2, acc2);
    acc3 = fmaf(w3, h3, acc3);
  }
  for (; i < end; ++i) {
    const int s = col[i];
    float lg = sa[s * H + head] + dv;
    lg = lg >= 0.f ? lg : LEAKY * lg;
    const float w = __expf(lg);
    ws0 += w;
    acc0 = fmaf(w, h[(size_t)s * HC + cc], acc0);
  }
  const float wsum = (ws0 + ws1) + (ws2 + ws3);
  const float acc = (acc0 + acc1) + (acc2 + acc3);

  float v = acc / fmaxf(wsum, 1e-16f) + h[(size_t)nc * HC + cc] + bias[cc];
  if constexpr (LN) {
    const float mu = wave_reduce_add64(v) * (1.f / 64.f);
    const float d = v - mu;
    const float var = wave_reduce_add64(d * d) * (1.f / 64.f);
    float y = d * rsqrtf(var + 1e-5f) * gamma[cc] + beta[cc];
    v = fmaxf(y, 0.f);
  }
  if (valid) out[(size_t)n * HC + cc] = v;
}

// ---------------- CSR build: LDS-staged radix partition ----------------
// All global atomics are pre-aggregated in LDS (<=196 ops per address).
// Scattered writes are reordered in LDS so flushes are bucket-contiguous.

// per-chunk LDS histogram -> bucket totals
__global__ __launch_bounds__(256)
void k_hist_chunk(const int* __restrict__ dst, int* __restrict__ bcnt, int E, int NB) {
  __shared__ int lh[NBMAX];
  const int t = (int)threadIdx.x;
  const int c0 = (int)blockIdx.x * CHUNK;
  const int cnt = min(CHUNK, E - c0);
  for (int b = t; b < NB; b += 256) lh[b] = 0;
  __syncthreads();
  for (int i = t; i < cnt; i += 256)
    atomicAdd(&lh[dst[c0 + i] >> BSH], 1);
  __syncthreads();
  for (int b = t; b < NB; b += 256)
    if (lh[b]) atomicAdd(&bcnt[b], lh[b]);
}

// one block: exclusive scan of bucket counts
__global__ void k_bscan(const int* __restrict__ bcnt, int nb,
                        int* __restrict__ bstart, int* __restrict__ bcur,
                        int* __restrict__ rowp_last, int E) {
  __shared__ int sm[256];
  const int t = (int)threadIdx.x;
  int v[4];
  #pragma unroll
  for (int j = 0; j < 4; ++j) { int i = t * 4 + j; v[j] = (i < nb) ? bcnt[i] : 0; }
  const int tot = v[0] + v[1] + v[2] + v[3];
  sm[t] = tot; __syncthreads();
  #pragma unroll
  for (int off = 1; off < 256; off <<= 1) {
    int xv = (t >= off) ? sm[t - off] : 0;
    __syncthreads();
    sm[t] += xv;
    __syncthreads();
  }
  int excl = sm[t] - tot;
  #pragma unroll
  for (int j = 0; j < 4; ++j) {
    int i = t * 4 + j;
    if (i < nb) { bstart[i] = excl; bcur[i] = excl; excl += v[j]; }
  }
  if (t == 0) { bstart[nb] = E; *rowp_last = E; }
}

// partition: LDS hist -> LDS scan -> bucket-sorted LDS stage -> contiguous flush
__global__ __launch_bounds__(256)
void k_part(const int* __restrict__ src, const int* __restrict__ dst,
            int* __restrict__ bcur, int* __restrict__ pairs, int E, int NB) {
  __shared__ int lh[NBMAX];     // hist, then local cursor
  __shared__ int lofs[NBMAX];   // exclusive local scan
  __shared__ int gofs[NBMAX];   // reserved global run base
  __shared__ int stg[CHUNK];    // packed pairs, bucket-sorted
  __shared__ short stgb[CHUNK]; // bucket id per staged slot
  __shared__ int bsum[256];
  const int t = (int)threadIdx.x;
  const int c0 = (int)blockIdx.x * CHUNK;
  const int cnt = min(CHUNK, E - c0);

  for (int b = t; b < NB; b += 256) lh[b] = 0;
  __syncthreads();
  for (int i = t; i < cnt; i += 256)
    atomicAdd(&lh[dst[c0 + i] >> BSH], 1);
  __syncthreads();

  // exclusive scan of lh (NB <= 1024): 4 serial per thread + block scan
  int v[4]; int run = 0;
  #pragma unroll
  for (int j = 0; j < 4; ++j) {
    const int b = t * 4 + j;
    v[j] = (b < NB) ? lh[b] : 0;
    run += v[j];
  }
  bsum[t] = run;
  __syncthreads();
  #pragma unroll
  for (int off = 1; off < 256; off <<= 1) {
    int xv = (t >= off) ? bsum[t - off] : 0;
    __syncthreads();
    bsum[t] += xv;
    __syncthreads();
  }
  int base = bsum[t] - run;
  #pragma unroll
  for (int j = 0; j < 4; ++j) {
    const int b = t * 4 + j;
    if (b < NB) lofs[b] = base;
    base += v[j];
  }
  __syncthreads();

  // reserve global runs (one atomic per (chunk,bucket)); lh becomes cursor
  for (int b = t; b < NB; b += 256) {
    const int c = lh[b];
    gofs[b] = c ? atomicAdd(&bcur[b], c) : 0;
    lh[b] = lofs[b];
  }
  __syncthreads();

  // place edges bucket-sorted into stage
  for (int i = t; i < cnt; i += 256) {
    const int d = dst[c0 + i];
    const int b = d >> BSH;
    const int p = atomicAdd(&lh[b], 1);
    stg[p] = (src[c0 + i] << BSH) | (d & (BN - 1));
    stgb[p] = (short)b;
  }
  __syncthreads();

  // flush: consecutive threads -> consecutive global addresses within runs
  for (int i = t; i < cnt; i += 256) {
    const int b = (int)stgb[i];
    pairs[gofs[b] + (i - lofs[b])] = stg[i];
  }
}

// one workgroup per bucket: LDS histogram + scan + LDS-cursor scatter.
__global__ __launch_bounds__(256)
void k_bucket_csr(const int* __restrict__ pairs, const int* __restrict__ bstart,
                  int* __restrict__ rowp, int* __restrict__ col, int N) {
  __shared__ int ldeg[BN];
  __shared__ int lofs[BN];
  const int b = (int)blockIdx.x;
  const int t = (int)threadIdx.x;
  const int base = b << BSH;
  const int nn = min(BN, N - base);
  const int s0 = bstart[b];
  const int s1 = bstart[b + 1];

  if (t < BN) ldeg[t] = 0;
  __syncthreads();
  for (int i = s0 + t; i < s1; i += 256)
    atomicAdd(&ldeg[pairs[i] & (BN - 1)], 1);
  __syncthreads();
  if (t < BN) lofs[t] = ldeg[t];
  __syncthreads();
  #pragma unroll
  for (int off = 1; off < BN; off <<= 1) {
    int v = (t < BN && t >= off) ? lofs[t - off] : 0;
    __syncthreads();
    if (t < BN) lofs[t] += v;
    __syncthreads();
  }
  if (t < BN) {
    const int ofs = s0 + lofs[t] - ldeg[t];
    if (t < nn) rowp[base + t] = ofs;
    ldeg[t] = ofs;
  }
  __syncthreads();
  for (int i = s0 + t; i < s1; i += 256) {
    const int pr = pairs[i];
    const int p = atomicAdd(&ldeg[pr & (BN - 1)], 1);
    col[p] = pr >> BSH;
  }
}

extern "C" void kernel_launch(void* const* d_in, const int* in_sizes, int n_in,
                              void* d_out, int out_size, void* d_ws, size_t ws_size,
                              hipStream_t stream) {
  const float* x   = (const float*)d_in[0];
  const int* esrc  = (const int*)d_in[1];
  const int* edst  = (const int*)d_in[2];
  const float* W1  = (const float*)d_in[3];
  const float* as1 = (const float*)d_in[4];
  const float* ad1 = (const float*)d_in[5];
  const float* b1  = (const float*)d_in[6];
  const float* W2  = (const float*)d_in[7];
  const float* as2 = (const float*)d_in[8];
  const float* ad2 = (const float*)d_in[9];
  const float* b2  = (const float*)d_in[10];
  const float* W3  = (const float*)d_in[11];
  const float* as3 = (const float*)d_in[12];
  const float* ad3 = (const float*)d_in[13];
  const float* b3  = (const float*)d_in[14];
  const float* g1  = (const float*)d_in[15];
  const float* be1 = (const float*)d_in[16];
  const float* g2  = (const float*)d_in[17];
  const float* be2 = (const float*)d_in[18];

  const int N = in_sizes[0] / 128;
  const int E = in_sizes[1];
  const int NB = (N + BN - 1) / BN;

  char* ws = (char*)d_ws;
  size_t off = 0;
  auto alloc = [&](size_t bytes) -> void* {
    void* p = ws + off;
    off = (off + bytes + 255) & ~(size_t)255;
    return p;
  };
  float* hbuf  = (float*)alloc((size_t)N * 64 * 4);
  float* lnbuf = (float*)alloc((size_t)N * 64 * 4);
  float* sab   = (float*)alloc((size_t)N * 2 * 4);
  float* dab   = (float*)alloc((size_t)N * 2 * 4);
  int* rowp    = (int*)alloc((size_t)(N + 1) * 4);
  int* colb    = (int*)alloc((size_t)E * 4);
  int* bcnt    = (int*)alloc((size_t)NB * 4);
  int* bstart  = (int*)alloc((size_t)(NB + 1) * 4);
  int* bcur    = (int*)alloc((size_t)NB * 4);
  // pairs buffer: reuse d_out (N*32 floats = 12.8MB >= E*4 = 6.4MB);
  // lifetime ends before the final layer writes d_out.
  int* pairs = (E <= out_size) ? (int*)d_out : (int*)alloc((size_t)E * 4);
  (void)ws_size; (void)n_in;

  // ---- CSR build (contention-free radix partition) ----
  hipMemsetAsync(bcnt, 0, (size_t)NB * 4, stream);
  const int NW = (E + CHUNK - 1) / CHUNK;
  k_hist_chunk<<<NW, 256, 0, stream>>>(edst, bcnt, E, NB);
  k_bscan<<<1, 256, 0, stream>>>(bcnt, NB, bstart, bcur, rowp + N, E);
  k_part<<<NW, 256, 0, stream>>>(esrc, edst, bcur, pairs, E, NB);
  k_bucket_csr<<<NB, 256, 0, stream>>>(pairs, bstart, rowp, colb, N);

  const int gG12 = (N + 63) / 64;
  const int gG3  = (N + 127) / 128;
  const int gEdge  = (N + 3) / 4;
  const int gEdge3 = (N + 7) / 8;

  // ---- Layer 1: 128 -> (2x32) + LN + ReLU ----
  gat_gemm2<128, 64, 2><<<gG12, 256, 0, stream>>>(x, W1, as1, ad1, hbuf, sab, dab, N);
  gat_edge<2, 32, true><<<gEdge, 256, 0, stream>>>(hbuf, sab, dab, rowp, colb, b1, g1, be1, lnbuf, N);

  // ---- Layer 2: 64 -> (2x32) + LN + ReLU ----
  gat_gemm2<64, 64, 2><<<gG12, 256, 0, stream>>>(lnbuf, W2, as2, ad2, hbuf, sab, dab, N);
  gat_edge<2, 32, true><<<gEdge, 256, 0, stream>>>(hbuf, sab, dab, rowp, colb, b2, g2, be2, lnbuf, N);

  // ---- Layer 3: 64 -> (1x32), no LN ----
  gat_gemm2<64, 32, 1><<<gG3, 256, 0, stream>>>(lnbuf, W3, as3, ad3, hbuf, sab, dab, N);
  gat_edge<1, 32, false><<<gEdge3, 256, 0, stream>>>(hbuf, sab, dab, rowp, colb, b3, nullptr, nullptr,
                                                     (float*)d_out, N);
}

// Round 5
// 351.928 us; speedup vs baseline: 3.0753x; 1.0394x over previous
//
#include <hip/hip_runtime.h>

#define LEAKY 0.2f
#define BSH 7
#define BN 128      // nodes per bucket = 1<<BSH
#define CHUNK 8192  // edges per partition workgroup
#define NBMAX 1024  // max buckets supported by LDS arrays

__device__ __forceinline__ float wave_reduce_add64(float v) {
  #pragma unroll
  for (int m = 1; m < 64; m <<= 1) v += __shfl_xor(v, m, 64);
  return v;
}

__device__ __forceinline__ float b2f(unsigned short u) {
  return __uint_as_float((unsigned int)u << 16);
}
__device__ __forceinline__ unsigned short f2b(float f) {
  unsigned int u = __float_as_uint(f);
  u += 0x7fffu + ((u >> 16) & 1u);   // round-to-nearest-even
  return (unsigned short)(u >> 16);
}

// ---------------- Tiled GEMM + fused attention dots (+ bf16 mirror of h) ----------------
template<int K, int CO, int H>
__global__ __launch_bounds__(256)
void gat_gemm2(const float* __restrict__ x, const float* __restrict__ W,
               const float* __restrict__ atts, const float* __restrict__ attd,
               float* __restrict__ h, unsigned short* __restrict__ hb,
               float* __restrict__ sa, float* __restrict__ da, int N) {
  constexpr int CG = CO / 4;
  constexpr int BM = (256 / CG) * 4;
  constexpr int BK = 64;
  constexpr int NK = K / BK;
  constexpr int C = CO / H;

  __shared__ float xs[BM][BK + 4];
  __shared__ float ws[CO][K + 4];

  const int t = (int)threadIdx.x;
  const int cg = t % CG;
  const int ng = t / CG;
  const int n0 = (int)blockIdx.x * BM;

  constexpr int WF4 = CO * K / 4;
  for (int f = t; f < WF4; f += 256) {
    const int r = f / (K / 4), c4 = f % (K / 4);
    *(float4*)&ws[r][c4 * 4] = *(const float4*)(W + (size_t)r * K + c4 * 4);
  }

  float acc[4][4] = {};

  for (int kb = 0; kb < NK; ++kb) {
    __syncthreads();
    constexpr int XF4 = BM * BK / 4;
    for (int f = t; f < XF4; f += 256) {
      const int r = f / (BK / 4), c4 = f % (BK / 4);
      int row = n0 + r; row = row < N ? row : N - 1;
      *(float4*)&xs[r][c4 * 4] = *(const float4*)(x + (size_t)row * K + kb * BK + c4 * 4);
    }
    __syncthreads();
    #pragma unroll
    for (int k = 0; k < BK; k += 4) {
      float4 xa[4], wb[4];
      #pragma unroll
      for (int i = 0; i < 4; ++i) xa[i] = *(const float4*)&xs[ng * 4 + i][k];
      #pragma unroll
      for (int j = 0; j < 4; ++j) wb[j] = *(const float4*)&ws[cg + CG * j][kb * BK + k];
      #pragma unroll
      for (int i = 0; i < 4; ++i) {
        #pragma unroll
        for (int j = 0; j < 4; ++j) {
          acc[i][j] = fmaf(xa[i].x, wb[j].x, acc[i][j]);
          acc[i][j] = fmaf(xa[i].y, wb[j].y, acc[i][j]);
          acc[i][j] = fmaf(xa[i].z, wb[j].z, acc[i][j]);
          acc[i][j] = fmaf(xa[i].w, wb[j].w, acc[i][j]);
        }
      }
    }
  }

  float as_[4], ad_[4];
  #pragma unroll
  for (int j = 0; j < 4; ++j) {
    as_[j] = atts[cg + CG * j];
    ad_[j] = attd[cg + CG * j];
  }
  float ps[4][H] = {}, pd[4][H] = {};
  #pragma unroll
  for (int i = 0; i < 4; ++i) {
    #pragma unroll
    for (int j = 0; j < 4; ++j) {
      const int hd = (CG * j) / C;
      ps[i][hd] = fmaf(acc[i][j], as_[j], ps[i][hd]);
      pd[i][hd] = fmaf(acc[i][j], ad_[j], pd[i][hd]);
    }
  }
  #pragma unroll
  for (int m = 1; m < CG; m <<= 1) {
    #pragma unroll
    for (int i = 0; i < 4; ++i) {
      #pragma unroll
      for (int hd = 0; hd < H; ++hd) {
        ps[i][hd] += __shfl_xor(ps[i][hd], m, 64);
        pd[i][hd] += __shfl_xor(pd[i][hd], m, 64);
      }
    }
  }

  #pragma unroll
  for (int i = 0; i < 4; ++i) {
    const int n = n0 + ng * 4 + i;
    if (n < N) {
      #pragma unroll
      for (int j = 0; j < 4; ++j) {
        h[(size_t)n * CO + cg + CG * j] = acc[i][j];
        hb[(size_t)n * CO + cg + CG * j] = f2b(acc[i][j]);
      }
      if (cg == 0) {
        #pragma unroll
        for (int hd = 0; hd < H; ++hd) {
          sa[n * H + hd] = ps[i][hd];
          da[n * H + hd] = pd[i][hd];
        }
      }
    }
  }
}

// ---------------- Edge aggregation, H=2 (64 channels), scalar col/sa, bf16 gather ----------------
template<bool LN>
__global__ __launch_bounds__(256)
void gat_edge2(const float* __restrict__ h, const unsigned short* __restrict__ hb,
               const float* __restrict__ sa, const float* __restrict__ da,
               const int* __restrict__ rowp, const int* __restrict__ col,
               const float* __restrict__ bias, const float* __restrict__ gamma,
               const float* __restrict__ beta, float* __restrict__ out, int N) {
  const int lane = (int)(threadIdx.x & 63);
  int wv = (int)((blockIdx.x * blockDim.x + threadIdx.x) >> 6);
  const int n = __builtin_amdgcn_readfirstlane(wv);
  if (n >= N) return;
  const int cc = lane;
  const int head = lane >> 5;
  const int beg = __builtin_amdgcn_readfirstlane(rowp[n]);
  const int end = __builtin_amdgcn_readfirstlane(rowp[n + 1]);
  const float dv = da[n * 2 + head];

  float acc0 = 0.f, acc1 = 0.f, acc2 = 0.f, acc3 = 0.f;
  float ws0 = 0.f, ws1 = 0.f, ws2 = 0.f, ws3 = 0.f;
  int i = beg;
  for (; i + 4 <= end; i += 4) {
    const int s0 = col[i], s1 = col[i + 1], s2 = col[i + 2], s3 = col[i + 3];
    const float2 p0 = *(const float2*)(sa + (size_t)s0 * 2);
    const float2 p1 = *(const float2*)(sa + (size_t)s1 * 2);
    const float2 p2 = *(const float2*)(sa + (size_t)s2 * 2);
    const float2 p3 = *(const float2*)(sa + (size_t)s3 * 2);
    const unsigned short u0 = hb[(size_t)s0 * 64 + cc];
    const unsigned short u1 = hb[(size_t)s1 * 64 + cc];
    const unsigned short u2 = hb[(size_t)s2 * 64 + cc];
    const unsigned short u3 = hb[(size_t)s3 * 64 + cc];
    float l0 = (head ? p0.y : p0.x) + dv;
    float l1 = (head ? p1.y : p1.x) + dv;
    float l2 = (head ? p2.y : p2.x) + dv;
    float l3 = (head ? p3.y : p3.x) + dv;
    l0 = l0 >= 0.f ? l0 : LEAKY * l0;
    l1 = l1 >= 0.f ? l1 : LEAKY * l1;
    l2 = l2 >= 0.f ? l2 : LEAKY * l2;
    l3 = l3 >= 0.f ? l3 : LEAKY * l3;
    const float w0 = __expf(l0), w1 = __expf(l1), w2 = __expf(l2), w3 = __expf(l3);
    ws0 += w0; ws1 += w1; ws2 += w2; ws3 += w3;
    acc0 = fmaf(w0, b2f(u0), acc0);
    acc1 = fmaf(w1, b2f(u1), acc1);
    acc2 = fmaf(w2, b2f(u2), acc2);
    acc3 = fmaf(w3, b2f(u3), acc3);
  }
  for (; i < end; ++i) {
    const int s = col[i];
    const float2 p = *(const float2*)(sa + (size_t)s * 2);
    const unsigned short u = hb[(size_t)s * 64 + cc];
    float lg = (head ? p.y : p.x) + dv;
    lg = lg >= 0.f ? lg : LEAKY * lg;
    const float w = __expf(lg);
    ws0 += w;
    acc0 = fmaf(w, b2f(u), acc0);
  }
  const float wsum = (ws0 + ws1) + (ws2 + ws3);
  const float acc = (acc0 + acc1) + (acc2 + acc3);

  float v = acc / fmaxf(wsum, 1e-16f) + h[(size_t)n * 64 + cc] + bias[cc];
  if constexpr (LN) {
    const float mu = wave_reduce_add64(v) * (1.f / 64.f);
    const float d = v - mu;
    const float var = wave_reduce_add64(d * d) * (1.f / 64.f);
    float y = d * rsqrtf(var + 1e-5f) * gamma[cc] + beta[cc];
    v = fmaxf(y, 0.f);
  }
  out[(size_t)n * 64 + cc] = v;
}

// ---------------- Edge aggregation, H=1 (32 channels): 2 edges per wave-step ----------------
__global__ __launch_bounds__(256)
void gat_edge1(const float* __restrict__ h, const unsigned short* __restrict__ hb,
               const float* __restrict__ sa, const float* __restrict__ da,
               const int* __restrict__ rowp, const int* __restrict__ col,
               const float* __restrict__ bias, float* __restrict__ out, int N) {
  const int lane = (int)(threadIdx.x & 63);
  int wv = (int)((blockIdx.x * blockDim.x + threadIdx.x) >> 6);
  const int n = __builtin_amdgcn_readfirstlane(wv);
  if (n >= N) return;
  const int half = lane >> 5;
  const int c = lane & 31;
  const int beg = __builtin_amdgcn_readfirstlane(rowp[n]);
  const int end = __builtin_amdgcn_readfirstlane(rowp[n + 1]);
  const float dv = da[n];

  float accA = 0.f, accB = 0.f, wsA = 0.f, wsB = 0.f;
  int i = beg;
  for (; i + 4 <= end; i += 4) {   // 4 edges = 2 pair-steps
    const int s0 = col[i], s1 = col[i + 1], s2 = col[i + 2], s3 = col[i + 3];
    const float a0 = sa[s0], a1 = sa[s1], a2 = sa[s2], a3 = sa[s3];
    const int sA = half ? s1 : s0;
    const int sB = half ? s3 : s2;
    const unsigned short uA = hb[(size_t)sA * 32 + c];
    const unsigned short uB = hb[(size_t)sB * 32 + c];
    float lA = (half ? a1 : a0) + dv;
    float lB = (half ? a3 : a2) + dv;
    lA = lA >= 0.f ? lA : LEAKY * lA;
    lB = lB >= 0.f ? lB : LEAKY * lB;
    const float wA = __expf(lA), wB = __expf(lB);
    wsA += wA; wsB += wB;
    accA = fmaf(wA, b2f(uA), accA);
    accB = fmaf(wB, b2f(uB), accB);
  }
  for (; i + 2 <= end; i += 2) {
    const int s0 = col[i], s1 = col[i + 1];
    const float a0 = sa[s0], a1 = sa[s1];
    const int sA = half ? s1 : s0;
    const unsigned short uA = hb[(size_t)sA * 32 + c];
    float lA = (half ? a1 : a0) + dv;
    lA = lA >= 0.f ? lA : LEAKY * lA;
    const float wA = __expf(lA);
    wsA += wA;
    accA = fmaf(wA, b2f(uA), accA);
  }
  if (i < end) {                    // odd tail: half 0 only
    const int s0 = col[i];
    const float a0 = sa[s0];
    const unsigned short u = hb[(size_t)s0 * 32 + c];
    float lg = a0 + dv;
    lg = lg >= 0.f ? lg : LEAKY * lg;
    const float w = half == 0 ? __expf(lg) : 0.f;
    wsA += w;
    accA = fmaf(w, b2f(u), accA);
  }
  float acc = accA + accB;
  float wsum = wsA + wsB;
  acc += __shfl_xor(acc, 32, 64);
  wsum += __shfl_xor(wsum, 32, 64);

  if (half == 0) {
    const float v = acc / fmaxf(wsum, 1e-16f) + h[(size_t)n * 32 + c] + bias[c];
    out[(size_t)n * 32 + c] = v;
  }
}

// ---------------- CSR build: LDS-staged radix partition ----------------
__global__ __launch_bounds__(256)
void k_hist_chunk(const int* __restrict__ dst, int* __restrict__ bcnt, int E, int NB) {
  __shared__ int lh[NBMAX];
  const int t = (int)threadIdx.x;
  const int c0 = (int)blockIdx.x * CHUNK;
  const int cnt = min(CHUNK, E - c0);
  for (int b = t; b < NB; b += 256) lh[b] = 0;
  __syncthreads();
  for (int i = t; i < cnt; i += 256)
    atomicAdd(&lh[dst[c0 + i] >> BSH], 1);
  __syncthreads();
  for (int b = t; b < NB; b += 256)
    if (lh[b]) atomicAdd(&bcnt[b], lh[b]);
}

__global__ void k_bscan(const int* __restrict__ bcnt, int nb,
                        int* __restrict__ bstart, int* __restrict__ bcur,
                        int* __restrict__ rowp_last, int E) {
  __shared__ int sm[256];
  const int t = (int)threadIdx.x;
  int v[4];
  #pragma unroll
  for (int j = 0; j < 4; ++j) { int i = t * 4 + j; v[j] = (i < nb) ? bcnt[i] : 0; }
  const int tot = v[0] + v[1] + v[2] + v[3];
  sm[t] = tot; __syncthreads();
  #pragma unroll
  for (int off = 1; off < 256; off <<= 1) {
    int xv = (t >= off) ? sm[t - off] : 0;
    __syncthreads();
    sm[t] += xv;
    __syncthreads();
  }
  int excl = sm[t] - tot;
  #pragma unroll
  for (int j = 0; j < 4; ++j) {
    int i = t * 4 + j;
    if (i < nb) { bstart[i] = excl; bcur[i] = excl; excl += v[j]; }
  }
  if (t == 0) { bstart[nb] = E; *rowp_last = E; }
}

__global__ __launch_bounds__(256)
void k_part(const int* __restrict__ src, const int* __restrict__ dst,
            int* __restrict__ bcur, int* __restrict__ pairs, int E, int NB) {
  __shared__ int lh[NBMAX];
  __shared__ int lofs[NBMAX];
  __shared__ int gofs[NBMAX];
  __shared__ int stg[CHUNK];
  __shared__ short stgb[CHUNK];
  __shared__ int bsum[256];
  const int t = (int)threadIdx.x;
  const int c0 = (int)blockIdx.x * CHUNK;
  const int cnt = min(CHUNK, E - c0);

  for (int b = t; b < NB; b += 256) lh[b] = 0;
  __syncthreads();
  for (int i = t; i < cnt; i += 256)
    atomicAdd(&lh[dst[c0 + i] >> BSH], 1);
  __syncthreads();

  int v[4]; int run = 0;
  #pragma unroll
  for (int j = 0; j < 4; ++j) {
    const int b = t * 4 + j;
    v[j] = (b < NB) ? lh[b] : 0;
    run += v[j];
  }
  bsum[t] = run;
  __syncthreads();
  #pragma unroll
  for (int off = 1; off < 256; off <<= 1) {
    int xv = (t >= off) ? bsum[t - off] : 0;
    __syncthreads();
    bsum[t] += xv;
    __syncthreads();
  }
  int base = bsum[t] - run;
  #pragma unroll
  for (int j = 0; j < 4; ++j) {
    const int b = t * 4 + j;
    if (b < NB) lofs[b] = base;
    base += v[j];
  }
  __syncthreads();

  for (int b = t; b < NB; b += 256) {
    const int c = lh[b];
    gofs[b] = c ? atomicAdd(&bcur[b], c) : 0;
    lh[b] = lofs[b];
  }
  __syncthreads();

  for (int i = t; i < cnt; i += 256) {
    const int d = dst[c0 + i];
    const int b = d >> BSH;
    const int p = atomicAdd(&lh[b], 1);
    stg[p] = (src[c0 + i] << BSH) | (d & (BN - 1));
    stgb[p] = (short)b;
  }
  __syncthreads();

  for (int i = t; i < cnt; i += 256) {
    const int b = (int)stgb[i];
    pairs[gofs[b] + (i - lofs[b])] = stg[i];
  }
}

__global__ __launch_bounds__(256)
void k_bucket_csr(const int* __restrict__ pairs, const int* __restrict__ bstart,
                  int* __restrict__ rowp, int* __restrict__ col, int N) {
  __shared__ int ldeg[BN];
  __shared__ int lofs[BN];
  const int b = (int)blockIdx.x;
  const int t = (int)threadIdx.x;
  const int base = b << BSH;
  const int nn = min(BN, N - base);
  const int s0 = bstart[b];
  const int s1 = bstart[b + 1];

  if (t < BN) ldeg[t] = 0;
  __syncthreads();
  for (int i = s0 + t; i < s1; i += 256)
    atomicAdd(&ldeg[pairs[i] & (BN - 1)], 1);
  __syncthreads();
  if (t < BN) lofs[t] = ldeg[t];
  __syncthreads();
  #pragma unroll
  for (int off = 1; off < BN; off <<= 1) {
    int v = (t < BN && t >= off) ? lofs[t - off] : 0;
    __syncthreads();
    if (t < BN) lofs[t] += v;
    __syncthreads();
  }
  if (t < BN) {
    const int ofs = s0 + lofs[t] - ldeg[t];
    if (t < nn) rowp[base + t] = ofs;
    ldeg[t] = ofs;
  }
  __syncthreads();
  for (int i = s0 + t; i < s1; i += 256) {
    const int pr = pairs[i];
    const int p = atomicAdd(&ldeg[pr & (BN - 1)], 1);
    col[p] = pr >> BSH;
  }
}

extern "C" void kernel_launch(void* const* d_in, const int* in_sizes, int n_in,
                              void* d_out, int out_size, void* d_ws, size_t ws_size,
                              hipStream_t stream) {
  const float* x   = (const float*)d_in[0];
  const int* esrc  = (const int*)d_in[1];
  const int* edst  = (const int*)d_in[2];
  const float* W1  = (const float*)d_in[3];
  const float* as1 = (const float*)d_in[4];
  const float* ad1 = (const float*)d_in[5];
  const float* b1  = (const float*)d_in[6];
  const float* W2  = (const float*)d_in[7];
  const float* as2 = (const float*)d_in[8];
  const float* ad2 = (const float*)d_in[9];
  const float* b2  = (const float*)d_in[10];
  const float* W3  = (const float*)d_in[11];
  const float* as3 = (const float*)d_in[12];
  const float* ad3 = (const float*)d_in[13];
  const float* b3  = (const float*)d_in[14];
  const float* g1  = (const float*)d_in[15];
  const float* be1 = (const float*)d_in[16];
  const float* g2  = (const float*)d_in[17];
  const float* be2 = (const float*)d_in[18];

  const int N = in_sizes[0] / 128;
  const int E = in_sizes[1];
  const int NB = (N + BN - 1) / BN;

  char* ws = (char*)d_ws;
  size_t off = 0;
  auto alloc = [&](size_t bytes) -> void* {
    void* p = ws + off;
    off = (off + bytes + 255) & ~(size_t)255;
    return p;
  };
  float* hbuf  = (float*)alloc((size_t)N * 64 * 4);
  float* lnbuf = (float*)alloc((size_t)N * 64 * 4);
  unsigned short* hb = (unsigned short*)alloc((size_t)N * 64 * 2);
  float* sab   = (float*)alloc((size_t)N * 2 * 4);
  float* dab   = (float*)alloc((size_t)N * 2 * 4);
  int* rowp    = (int*)alloc((size_t)(N + 1) * 4);
  int* colb    = (int*)alloc((size_t)E * 4);
  int* bcnt    = (int*)alloc((size_t)NB * 4);
  int* bstart  = (int*)alloc((size_t)(NB + 1) * 4);
  int* bcur    = (int*)alloc((size_t)NB * 4);
  // pairs buffer: reuse d_out (N*32 floats = 12.8MB >= E*4 = 6.4MB);
  // lifetime ends before the final layer writes d_out.
  int* pairs = (E <= out_size) ? (int*)d_out : (int*)alloc((size_t)E * 4);
  (void)ws_size; (void)n_in;

  // ---- CSR build (contention-free radix partition) ----
  hipMemsetAsync(bcnt, 0, (size_t)NB * 4, stream);
  const int NW = (E + CHUNK - 1) / CHUNK;
  k_hist_chunk<<<NW, 256, 0, stream>>>(edst, bcnt, E, NB);
  k_bscan<<<1, 256, 0, stream>>>(bcnt, NB, bstart, bcur, rowp + N, E);
  k_part<<<NW, 256, 0, stream>>>(esrc, edst, bcur, pairs, E, NB);
  k_bucket_csr<<<NB, 256, 0, stream>>>(pairs, bstart, rowp, colb, N);

  const int gG12 = (N + 63) / 64;
  const int gG3  = (N + 127) / 128;
  const int gEdge = (N + 3) / 4;   // one wave per node

  // ---- Layer 1: 128 -> (2x32) + LN + ReLU ----
  gat_gemm2<128, 64, 2><<<gG12, 256, 0, stream>>>(x, W1, as1, ad1, hbuf, hb, sab, dab, N);
  gat_edge2<true><<<gEdge, 256, 0, stream>>>(hbuf, hb, sab, dab, rowp, colb, b1, g1, be1, lnbuf, N);

  // ---- Layer 2: 64 -> (2x32) + LN + ReLU ----
  gat_gemm2<64, 64, 2><<<gG12, 256, 0, stream>>>(lnbuf, W2, as2, ad2, hbuf, hb, sab, dab, N);
  gat_edge2<true><<<gEdge, 256, 0, stream>>>(hbuf, hb, sab, dab, rowp, colb, b2, g2, be2, lnbuf, N);

  // ---- Layer 3: 64 -> (1x32), no LN ----
  gat_gemm2<64, 32, 1><<<gG3, 256, 0, stream>>>(lnbuf, W3, as3, ad3, hbuf, hb, sab, dab, N);
  gat_edge1<<<gEdge, 256, 0, stream>>>(hbuf, hb, sab, dab, rowp, colb, b3, (float*)d_out, N);
}

// Round 6
// 333.453 us; speedup vs baseline: 3.2457x; 1.0554x over previous
//
#include <hip/hip_runtime.h>

#define LEAKY 0.2f
#define BSH 7
#define BN 128      // nodes per bucket = 1<<BSH
#define CHUNK 8192  // edges per partition workgroup
#define NBMAX 1024  // max buckets supported by LDS arrays

__device__ __forceinline__ float wave_reduce_add64(float v) {
  #pragma unroll
  for (int m = 1; m < 64; m <<= 1) v += __shfl_xor(v, m, 64);
  return v;
}

__device__ __forceinline__ float b2f(unsigned short u) {
  return __uint_as_float((unsigned int)u << 16);
}
__device__ __forceinline__ unsigned short f2b(float f) {
  unsigned int u = __float_as_uint(f);
  u += 0x7fffu + ((u >> 16) & 1u);   // round-to-nearest-even
  return (unsigned short)(u >> 16);
}

__device__ __forceinline__ float leaky(float l) {
  return l >= 0.f ? l : LEAKY * l;
}

// ---------------- Tiled GEMM + fused attention dots (+ bf16 mirror of h) ----------------
template<int K, int CO, int H>
__global__ __launch_bounds__(256)
void gat_gemm2(const float* __restrict__ x, const float* __restrict__ W,
               const float* __restrict__ atts, const float* __restrict__ attd,
               float* __restrict__ h, unsigned short* __restrict__ hb,
               float* __restrict__ sa, float* __restrict__ da, int N) {
  constexpr int CG = CO / 4;
  constexpr int BM = (256 / CG) * 4;
  constexpr int BK = 64;
  constexpr int NK = K / BK;
  constexpr int C = CO / H;

  __shared__ float xs[BM][BK + 4];
  __shared__ float ws[CO][K + 4];

  const int t = (int)threadIdx.x;
  const int cg = t % CG;
  const int ng = t / CG;
  const int n0 = (int)blockIdx.x * BM;

  constexpr int WF4 = CO * K / 4;
  for (int f = t; f < WF4; f += 256) {
    const int r = f / (K / 4), c4 = f % (K / 4);
    *(float4*)&ws[r][c4 * 4] = *(const float4*)(W + (size_t)r * K + c4 * 4);
  }

  float acc[4][4] = {};

  for (int kb = 0; kb < NK; ++kb) {
    __syncthreads();
    constexpr int XF4 = BM * BK / 4;
    for (int f = t; f < XF4; f += 256) {
      const int r = f / (BK / 4), c4 = f % (BK / 4);
      int row = n0 + r; row = row < N ? row : N - 1;
      *(float4*)&xs[r][c4 * 4] = *(const float4*)(x + (size_t)row * K + kb * BK + c4 * 4);
    }
    __syncthreads();
    #pragma unroll
    for (int k = 0; k < BK; k += 4) {
      float4 xa[4], wb[4];
      #pragma unroll
      for (int i = 0; i < 4; ++i) xa[i] = *(const float4*)&xs[ng * 4 + i][k];
      #pragma unroll
      for (int j = 0; j < 4; ++j) wb[j] = *(const float4*)&ws[cg + CG * j][kb * BK + k];
      #pragma unroll
      for (int i = 0; i < 4; ++i) {
        #pragma unroll
        for (int j = 0; j < 4; ++j) {
          acc[i][j] = fmaf(xa[i].x, wb[j].x, acc[i][j]);
          acc[i][j] = fmaf(xa[i].y, wb[j].y, acc[i][j]);
          acc[i][j] = fmaf(xa[i].z, wb[j].z, acc[i][j]);
          acc[i][j] = fmaf(xa[i].w, wb[j].w, acc[i][j]);
        }
      }
    }
  }

  float as_[4], ad_[4];
  #pragma unroll
  for (int j = 0; j < 4; ++j) {
    as_[j] = atts[cg + CG * j];
    ad_[j] = attd[cg + CG * j];
  }
  float ps[4][H] = {}, pd[4][H] = {};
  #pragma unroll
  for (int i = 0; i < 4; ++i) {
    #pragma unroll
    for (int j = 0; j < 4; ++j) {
      const int hd = (CG * j) / C;
      ps[i][hd] = fmaf(acc[i][j], as_[j], ps[i][hd]);
      pd[i][hd] = fmaf(acc[i][j], ad_[j], pd[i][hd]);
    }
  }
  #pragma unroll
  for (int m = 1; m < CG; m <<= 1) {
    #pragma unroll
    for (int i = 0; i < 4; ++i) {
      #pragma unroll
      for (int hd = 0; hd < H; ++hd) {
        ps[i][hd] += __shfl_xor(ps[i][hd], m, 64);
        pd[i][hd] += __shfl_xor(pd[i][hd], m, 64);
      }
    }
  }

  #pragma unroll
  for (int i = 0; i < 4; ++i) {
    const int n = n0 + ng * 4 + i;
    if (n < N) {
      #pragma unroll
      for (int j = 0; j < 4; ++j) {
        h[(size_t)n * CO + cg + CG * j] = acc[i][j];
        hb[(size_t)n * CO + cg + CG * j] = f2b(acc[i][j]);
      }
      if (cg == 0) {
        #pragma unroll
        for (int hd = 0; hd < H; ++hd) {
          sa[n * H + hd] = ps[i][hd];
          da[n * H + hd] = pd[i][hd];
        }
      }
    }
  }
}

// ---------------- Edge aggregation, H=2 (64 channels) ----------------
// Per 64-edge block: lane j computes softmax weight of edge beg+j ONCE
// (instead of 32x redundantly), stashes in LDS; fma loop reads w via
// broadcast ds_read, col via scalar loads -> ~4 VALU per edge wave-wide.
template<bool LN>
__global__ __launch_bounds__(256)
void gat_edge2(const float* __restrict__ h, const unsigned short* __restrict__ hb,
               const float* __restrict__ sa, const float* __restrict__ da,
               const int* __restrict__ rowp, const int* __restrict__ col,
               const float* __restrict__ bias, const float* __restrict__ gamma,
               const float* __restrict__ beta, float* __restrict__ out, int N) {
  __shared__ float wst[4][64][2];
  const int lane = (int)(threadIdx.x & 63);
  const int wib = (int)(threadIdx.x >> 6);
  int wv = (int)((blockIdx.x * blockDim.x + threadIdx.x) >> 6);
  const int n = __builtin_amdgcn_readfirstlane(wv);
  if (n >= N) return;
  const int cc = lane;
  const int head = lane >> 5;
  const int beg = __builtin_amdgcn_readfirstlane(rowp[n]);
  const int end = __builtin_amdgcn_readfirstlane(rowp[n + 1]);
  const float dv0 = da[n * 2];
  const float dv1 = da[n * 2 + 1];

  float a0 = 0.f, a1 = 0.f, a2 = 0.f, a3 = 0.f;
  float q0 = 0.f, q1 = 0.f, q2 = 0.f, q3 = 0.f;

  for (int b0 = beg; b0 < end; b0 += 64) {
    const int cnt = min(64, end - b0);
    if (lane < cnt) {
      const int s = col[b0 + lane];
      const float2 p = *(const float2*)(sa + (size_t)s * 2);
      wst[wib][lane][0] = __expf(leaky(p.x + dv0));
      wst[wib][lane][1] = __expf(leaky(p.y + dv1));
    }
    int i = 0;
    for (; i + 4 <= cnt; i += 4) {
      const int s0 = col[b0 + i],     s1 = col[b0 + i + 1];
      const int s2 = col[b0 + i + 2], s3 = col[b0 + i + 3];
      const float w0 = wst[wib][i][head];
      const float w1 = wst[wib][i + 1][head];
      const float w2 = wst[wib][i + 2][head];
      const float w3 = wst[wib][i + 3][head];
      q0 += w0; q1 += w1; q2 += w2; q3 += w3;
      a0 = fmaf(w0, b2f(hb[(size_t)s0 * 64 + cc]), a0);
      a1 = fmaf(w1, b2f(hb[(size_t)s1 * 64 + cc]), a1);
      a2 = fmaf(w2, b2f(hb[(size_t)s2 * 64 + cc]), a2);
      a3 = fmaf(w3, b2f(hb[(size_t)s3 * 64 + cc]), a3);
    }
    for (; i < cnt; ++i) {
      const int s = col[b0 + i];
      const float w = wst[wib][i][head];
      q0 += w;
      a0 = fmaf(w, b2f(hb[(size_t)s * 64 + cc]), a0);
    }
  }
  const float wsum = (q0 + q1) + (q2 + q3);
  const float acc = (a0 + a1) + (a2 + a3);

  float v = acc / fmaxf(wsum, 1e-16f) + h[(size_t)n * 64 + cc] + bias[cc];
  if constexpr (LN) {
    const float mu = wave_reduce_add64(v) * (1.f / 64.f);
    const float d = v - mu;
    const float var = wave_reduce_add64(d * d) * (1.f / 64.f);
    float y = d * rsqrtf(var + 1e-5f) * gamma[cc] + beta[cc];
    v = fmaxf(y, 0.f);
  }
  out[(size_t)n * 64 + cc] = v;
}

// ---------------- Edge aggregation, H=1 (32 channels): 2 edges/step ----------------
__global__ __launch_bounds__(256)
void gat_edge1(const float* __restrict__ h, const unsigned short* __restrict__ hb,
               const float* __restrict__ sa, const float* __restrict__ da,
               const int* __restrict__ rowp, const int* __restrict__ col,
               const float* __restrict__ bias, float* __restrict__ out, int N) {
  __shared__ float wst[4][64];
  const int lane = (int)(threadIdx.x & 63);
  const int wib = (int)(threadIdx.x >> 6);
  int wv = (int)((blockIdx.x * blockDim.x + threadIdx.x) >> 6);
  const int n = __builtin_amdgcn_readfirstlane(wv);
  if (n >= N) return;
  const int half = lane >> 5;
  const int c = lane & 31;
  const int beg = __builtin_amdgcn_readfirstlane(rowp[n]);
  const int end = __builtin_amdgcn_readfirstlane(rowp[n + 1]);
  const float dv = da[n];

  float aA = 0.f, aB = 0.f, qA = 0.f, qB = 0.f;

  for (int b0 = beg; b0 < end; b0 += 64) {
    const int cnt = min(64, end - b0);
    if (lane < cnt) {
      const int s = col[b0 + lane];
      wst[wib][lane] = __expf(leaky(sa[s] + dv));
    }
    int i = 0;
    for (; i + 4 <= cnt; i += 4) {
      const int s0 = col[b0 + i],     s1 = col[b0 + i + 1];
      const int s2 = col[b0 + i + 2], s3 = col[b0 + i + 3];
      const int sA = half ? s1 : s0;
      const int sB = half ? s3 : s2;
      const float wA = wst[wib][i + half];
      const float wB = wst[wib][i + 2 + half];
      qA += wA; qB += wB;
      aA = fmaf(wA, b2f(hb[(size_t)sA * 32 + c]), aA);
      aB = fmaf(wB, b2f(hb[(size_t)sB * 32 + c]), aB);
    }
    for (; i + 2 <= cnt; i += 2) {
      const int s0 = col[b0 + i], s1 = col[b0 + i + 1];
      const int sA = half ? s1 : s0;
      const float wA = wst[wib][i + half];
      qA += wA;
      aA = fmaf(wA, b2f(hb[(size_t)sA * 32 + c]), aA);
    }
    if (i < cnt) {   // odd tail: half 0 only
      const int s0 = col[b0 + i];
      const float wA = half ? 0.f : wst[wib][i];
      qA += wA;
      aA = fmaf(wA, b2f(hb[(size_t)s0 * 32 + c]), aA);
    }
  }
  float acc = aA + aB;
  float wsum = qA + qB;
  acc += __shfl_xor(acc, 32, 64);
  wsum += __shfl_xor(wsum, 32, 64);

  if (half == 0) {
    const float v = acc / fmaxf(wsum, 1e-16f) + h[(size_t)n * 32 + c] + bias[c];
    out[(size_t)n * 32 + c] = v;
  }
}

// ---------------- CSR build: LDS-staged radix partition ----------------
__global__ __launch_bounds__(256)
void k_hist_chunk(const int* __restrict__ dst, int* __restrict__ bcnt, int E, int NB) {
  __shared__ int lh[NBMAX];
  const int t = (int)threadIdx.x;
  const int c0 = (int)blockIdx.x * CHUNK;
  const int cnt = min(CHUNK, E - c0);
  for (int b = t; b < NB; b += 256) lh[b] = 0;
  __syncthreads();
  for (int i = t; i < cnt; i += 256)
    atomicAdd(&lh[dst[c0 + i] >> BSH], 1);
  __syncthreads();
  for (int b = t; b < NB; b += 256)
    if (lh[b]) atomicAdd(&bcnt[b], lh[b]);
}

__global__ void k_bscan(const int* __restrict__ bcnt, int nb,
                        int* __restrict__ bstart, int* __restrict__ bcur,
                        int* __restrict__ rowp_last, int E) {
  __shared__ int sm[256];
  const int t = (int)threadIdx.x;
  int v[4];
  #pragma unroll
  for (int j = 0; j < 4; ++j) { int i = t * 4 + j; v[j] = (i < nb) ? bcnt[i] : 0; }
  const int tot = v[0] + v[1] + v[2] + v[3];
  sm[t] = tot; __syncthreads();
  #pragma unroll
  for (int off = 1; off < 256; off <<= 1) {
    int xv = (t >= off) ? sm[t - off] : 0;
    __syncthreads();
    sm[t] += xv;
    __syncthreads();
  }
  int excl = sm[t] - tot;
  #pragma unroll
  for (int j = 0; j < 4; ++j) {
    int i = t * 4 + j;
    if (i < nb) { bstart[i] = excl; bcur[i] = excl; excl += v[j]; }
  }
  if (t == 0) { bstart[nb] = E; *rowp_last = E; }
}

__global__ __launch_bounds__(256)
void k_part(const int* __restrict__ src, const int* __restrict__ dst,
            int* __restrict__ bcur, int* __restrict__ pairs, int E, int NB) {
  __shared__ int lh[NBMAX];
  __shared__ int lofs[NBMAX];
  __shared__ int gofs[NBMAX];
  __shared__ int stg[CHUNK];
  __shared__ short stgb[CHUNK];
  __shared__ int bsum[256];
  const int t = (int)threadIdx.x;
  const int c0 = (int)blockIdx.x * CHUNK;
  const int cnt = min(CHUNK, E - c0);

  for (int b = t; b < NB; b += 256) lh[b] = 0;
  __syncthreads();
  for (int i = t; i < cnt; i += 256)
    atomicAdd(&lh[dst[c0 + i] >> BSH], 1);
  __syncthreads();

  int v[4]; int run = 0;
  #pragma unroll
  for (int j = 0; j < 4; ++j) {
    const int b = t * 4 + j;
    v[j] = (b < NB) ? lh[b] : 0;
    run += v[j];
  }
  bsum[t] = run;
  __syncthreads();
  #pragma unroll
  for (int off = 1; off < 256; off <<= 1) {
    int xv = (t >= off) ? bsum[t - off] : 0;
    __syncthreads();
    bsum[t] += xv;
    __syncthreads();
  }
  int base = bsum[t] - run;
  #pragma unroll
  for (int j = 0; j < 4; ++j) {
    const int b = t * 4 + j;
    if (b < NB) lofs[b] = base;
    base += v[j];
  }
  __syncthreads();

  for (int b = t; b < NB; b += 256) {
    const int c = lh[b];
    gofs[b] = c ? atomicAdd(&bcur[b], c) : 0;
    lh[b] = lofs[b];
  }
  __syncthreads();

  for (int i = t; i < cnt; i += 256) {
    const int d = dst[c0 + i];
    const int b = d >> BSH;
    const int p = atomicAdd(&lh[b], 1);
    stg[p] = (src[c0 + i] << BSH) | (d & (BN - 1));
    stgb[p] = (short)b;
  }
  __syncthreads();

  for (int i = t; i < cnt; i += 256) {
    const int b = (int)stgb[i];
    pairs[gofs[b] + (i - lofs[b])] = stg[i];
  }
}

__global__ __launch_bounds__(256)
void k_bucket_csr(const int* __restrict__ pairs, const int* __restrict__ bstart,
                  int* __restrict__ rowp, int* __restrict__ col, int N) {
  __shared__ int ldeg[BN];
  __shared__ int lofs[BN];
  const int b = (int)blockIdx.x;
  const int t = (int)threadIdx.x;
  const int base = b << BSH;
  const int nn = min(BN, N - base);
  const int s0 = bstart[b];
  const int s1 = bstart[b + 1];

  if (t < BN) ldeg[t] = 0;
  __syncthreads();
  for (int i = s0 + t; i < s1; i += 256)
    atomicAdd(&ldeg[pairs[i] & (BN - 1)], 1);
  __syncthreads();
  if (t < BN) lofs[t] = ldeg[t];
  __syncthreads();
  #pragma unroll
  for (int off = 1; off < BN; off <<= 1) {
    int v = (t < BN && t >= off) ? lofs[t - off] : 0;
    __syncthreads();
    if (t < BN) lofs[t] += v;
    __syncthreads();
  }
  if (t < BN) {
    const int ofs = s0 + lofs[t] - ldeg[t];
    if (t < nn) rowp[base + t] = ofs;
    ldeg[t] = ofs;
  }
  __syncthreads();
  for (int i = s0 + t; i < s1; i += 256) {
    const int pr = pairs[i];
    const int p = atomicAdd(&ldeg[pr & (BN - 1)], 1);
    col[p] = pr >> BSH;
  }
}

extern "C" void kernel_launch(void* const* d_in, const int* in_sizes, int n_in,
                              void* d_out, int out_size, void* d_ws, size_t ws_size,
                              hipStream_t stream) {
  const float* x   = (const float*)d_in[0];
  const int* esrc  = (const int*)d_in[1];
  const int* edst  = (const int*)d_in[2];
  const float* W1  = (const float*)d_in[3];
  const float* as1 = (const float*)d_in[4];
  const float* ad1 = (const float*)d_in[5];
  const float* b1  = (const float*)d_in[6];
  const float* W2  = (const float*)d_in[7];
  const float* as2 = (const float*)d_in[8];
  const float* ad2 = (const float*)d_in[9];
  const float* b2  = (const float*)d_in[10];
  const float* W3  = (const float*)d_in[11];
  const float* as3 = (const float*)d_in[12];
  const float* ad3 = (const float*)d_in[13];
  const float* b3  = (const float*)d_in[14];
  const float* g1  = (const float*)d_in[15];
  const float* be1 = (const float*)d_in[16];
  const float* g2  = (const float*)d_in[17];
  const float* be2 = (const float*)d_in[18];

  const int N = in_sizes[0] / 128;
  const int E = in_sizes[1];
  const int NB = (N + BN - 1) / BN;

  char* ws = (char*)d_ws;
  size_t off = 0;
  auto alloc = [&](size_t bytes) -> void* {
    void* p = ws + off;
    off = (off + bytes + 255) & ~(size_t)255;
    return p;
  };
  float* hbuf  = (float*)alloc((size_t)N * 64 * 4);
  float* lnbuf = (float*)alloc((size_t)N * 64 * 4);
  unsigned short* hb = (unsigned short*)alloc((size_t)N * 64 * 2);
  float* sab   = (float*)alloc((size_t)N * 2 * 4);
  float* dab   = (float*)alloc((size_t)N * 2 * 4);
  int* rowp    = (int*)alloc((size_t)(N + 1) * 4);
  int* colb    = (int*)alloc((size_t)E * 4);
  int* bcnt    = (int*)alloc((size_t)NB * 4);
  int* bstart  = (int*)alloc((size_t)(NB + 1) * 4);
  int* bcur    = (int*)alloc((size_t)NB * 4);
  // pairs buffer: reuse d_out (N*32 floats = 12.8MB >= E*4 = 6.4MB);
  // lifetime ends before the final layer writes d_out.
  int* pairs = (E <= out_size) ? (int*)d_out : (int*)alloc((size_t)E * 4);
  (void)ws_size; (void)n_in;

  // ---- CSR build (contention-free radix partition) ----
  hipMemsetAsync(bcnt, 0, (size_t)NB * 4, stream);
  const int NW = (E + CHUNK - 1) / CHUNK;
  k_hist_chunk<<<NW, 256, 0, stream>>>(edst, bcnt, E, NB);
  k_bscan<<<1, 256, 0, stream>>>(bcnt, NB, bstart, bcur, rowp + N, E);
  k_part<<<NW, 256, 0, stream>>>(esrc, edst, bcur, pairs, E, NB);
  k_bucket_csr<<<NB, 256, 0, stream>>>(pairs, bstart, rowp, colb, N);

  const int gG12 = (N + 63) / 64;
  const int gG3  = (N + 127) / 128;
  const int gEdge = (N + 3) / 4;   // one wave per node

  // ---- Layer 1: 128 -> (2x32) + LN + ReLU ----
  gat_gemm2<128, 64, 2><<<gG12, 256, 0, stream>>>(x, W1, as1, ad1, hbuf, hb, sab, dab, N);
  gat_edge2<true><<<gEdge, 256, 0, stream>>>(hbuf, hb, sab, dab, rowp, colb, b1, g1, be1, lnbuf, N);

  // ---- Layer 2: 64 -> (2x32) + LN + ReLU ----
  gat_gemm2<64, 64, 2><<<gG12, 256, 0, stream>>>(lnbuf, W2, as2, ad2, hbuf, hb, sab, dab, N);
  gat_edge2<true><<<gEdge, 256, 0, stream>>>(hbuf, hb, sab, dab, rowp, colb, b2, g2, be2, lnbuf, N);

  // ---- Layer 3: 64 -> (1x32), no LN ----
  gat_gemm2<64, 32, 1><<<gG3, 256, 0, stream>>>(lnbuf, W3, as3, ad3, hbuf, hb, sab, dab, N);
  gat_edge1<<<gEdge, 256, 0, stream>>>(hbuf, hb, sab, dab, rowp, colb, b3, (float*)d_out, N);
}